// Round 13
// baseline (173.344 us; speedup 1.0000x reference)
//
#include <hip/hip_runtime.h>
#include <math.h>

#define T 32
#define K 2048
#define NBLOCKS 256
#define NTHREADS 1024
#define NWAVES 16
#define HB 128                          // blocks per direction
#define CPB 16                          // columns per block (1 per wave)
#define L2E_F 1.4426950408889634f       // log2(e)
#define LN2_F 0.6931471805599453f
#define LOG2PI_F 1.8378770664093453f
#define SP_F     0.17677669529663687f   // sqrt(1/32)
#define LOG_SP_F (-1.7328679513998633f) // ln(sqrt(1/32))
#define CNORM_F  (-(LOG_SP_F) - 0.5f * LOG2PI_F)   // -ln(sp) - 0.5 ln2pi

#if __has_builtin(__builtin_amdgcn_exp2f)
#define EXP2F(x) __builtin_amdgcn_exp2f(x)
#else
#define EXP2F(x) exp2f(x)
#endif
#if __has_builtin(__builtin_amdgcn_logf)
#define LOG2F(x) __builtin_amdgcn_logf(x)
#else
#define LOG2F(x) log2f(x)
#endif

// ALL global sync traffic is relaxed agent-scope atomics (write-through to
// the MALL, bypassing non-coherent per-XCD L2s). NO agent-scope
// release/acquire anywhere (R2/R7: ~15us/step of L2 cache maintenance).
__device__ __forceinline__ float aload4(const float* p) {
    return __hip_atomic_load(p, __ATOMIC_RELAXED, __HIP_MEMORY_SCOPE_AGENT);
}
__device__ __forceinline__ void astore4(float* p, float v) {
    __hip_atomic_store(p, v, __ATOMIC_RELAXED, __HIP_MEMORY_SCOPE_AGENT);
}
__device__ __forceinline__ int sload(const int* p) {
    return __hip_atomic_load(p, __ATOMIC_RELAXED, __HIP_MEMORY_SCOPE_AGENT);
}
__device__ __forceinline__ void sstore(int* p, int v) {
    __hip_atomic_store(p, v, __ATOMIC_RELAXED, __HIP_MEMORY_SCOPE_AGENT);
}

// Bidirectional meet-in-the-middle (R11: 16 fwd / 15 bwd steps) with R11's
// MALL protocol (128 packed sentinels/direction, wave-0 poll + LDS stepflag
// handoff, ONE-SHOT row read — R12's per-wave message polling quadrupled
// FETCH_SIZE) and R12's barrier-free block interior:
//  - each wave stages only its own 128-slot chunk, raises an LDS chunkflag
//    (workgroup release = lgkmcnt only); max-pass streams chunks
//    round-robin in arrival order (LDS spins are CU-local, free)
//  - after publishing its column, each wave drains its own stores
//    (s_waitcnt vmcnt(0)) and bumps an LDS counter; the 16th wave fires the
//    block sentinel. Early waves run ahead into the next step's detection.
// Sentinel ordering without barriers: the sentinel for step p+2 is only
// stored after every wave passed step-(p+1) work, which required wave 0's
// detection of ALL sentinels >= p+1 — i.e. the p+1 sentinel was already
// visible at the MALL before the p+2 store issues. Ping-pong safety: the
// usual full-consumption-before-production induction; LDS parity reuse is
// guarded by per-wave done-flags. Signed sentinels 1..17: the 0xAAAAAAAA
// poison is negative and never satisfies >=, so no init kernel is needed.
__global__ __launch_bounds__(NTHREADS) void fused_kernel(
    const float* __restrict__ means, const float* __restrict__ log_stds,
    const float* __restrict__ eps, float* __restrict__ fbuf,
    float* __restrict__ bbuf, int* __restrict__ fsent, int* __restrict__ bsent,
    float* __restrict__ out)
{
    __shared__ float2 shzD[2][K];    // 32 KB: (z_j, D_j) staging, parity dbuf
    __shared__ float2 lzc[T][CPB];   // own cols: (32*L2E*z, cm2 const)
    __shared__ float smu[T], sstd[T], slq2[T];
    __shared__ float red[NTHREADS];
    __shared__ int chunkflag[2][NWAVES];
    __shared__ int donef[2][NWAVES];
    __shared__ int pubcnt[2];
    __shared__ int stepflag;

    const int tid  = threadIdx.x;
    const int b    = blockIdx.x;
    const bool fwd = (b < HB);
    const int lb   = fwd ? b : b - HB;
    const int col0 = lb * CPB;

    if (tid < 2 * NWAVES)           ((int*)chunkflag)[tid] = 0;
    else if (tid < 4 * NWAVES)      ((int*)donef)[tid - 2 * NWAVES] = 0;
    else if (tid == 4 * NWAVES)     { pubcnt[0] = 0; pubcnt[1] = 0; stepflag = 0; }

    // ---- setup: threads 0..511, thread (t = tid>>4, dcol = tid&15) ----
    if (tid < T * CPB) {
        int t = tid >> 4, dcol = tid & 15;
        float mu = means[t];
        float st = expf(log_stds[t]);
        if (dcol == 0) {
            smu[t] = mu; sstd[t] = st;
            slq2[t] = L2E_F * (logf(st) + 0.5f * LOG2PI_F);
        }
        float e = eps[t * K + col0 + dcol];
        float z = fmaf(st, e, mu);
        // (z-mu)/st == e exactly: log_q = -0.5 e^2 - ln(st) - 0.5 ln2pi
        float log_q = fmaf(-0.5f * e, e, -logf(st) - 0.5f * LOG2PI_F);
        float tz2 = (32.0f * L2E_F) * z;
        if (fwd) {
            float cm2 = fmaf((-16.0f * L2E_F) * z, z,
                             L2E_F * (CNORM_F - log_q)) - 11.0f;   // log2K = 11
            lzc[t][dcol] = make_float2(tz2, cm2);
            if (t == 0) {   // seed r_0, parity 0
                float r0 = fmaf(-16.0f * z, z, CNORM_F) - log_q;
                astore4(&fbuf[col0 + dcol], r0 * L2E_F);
            }
        } else {
            float cm2 = fmaf((-16.0f * L2E_F) * z, z, L2E_F * CNORM_F) - 11.0f;
            lzc[t][dcol] = make_float2(tz2, cm2);
            if (t == T - 1) {   // seed c_31 = likelihood, parity 0
                float d = 0.5f - z;
                float c31 = fmaf(-0.5f * d, d, -0.5f * LOG2PI_F);
                astore4(&bbuf[col0 + dcol], c31 * L2E_F);
            }
        }
    }
    __syncthreads();    // LDS init visible + seed stores vmcnt-drained
    int* mysent = fwd ? fsent : bsent;
    if (tid == 0) sstore(&mysent[lb], 1);

    const int lane = tid & 63;
    const int wave = tid >> 6;          // 0..15: column col0 + wave, chunk id
    float* mybuf = fwd ? fbuf : bbuf;
    const int nstep = fwd ? 16 : 15;
    const int j0 = wave * 128 + lane;
    const int j1 = j0 + 64;

    for (int p = 0; p < nstep; ++p) {
        const int par  = p & 1;
        const int tg   = p + 1;
        const int tin  = fwd ? p : 31 - p;
        const int town = fwd ? p + 1 : 30 - p;
        const float mu_i  = smu[tin];
        const float std_i = sstd[tin];
        const float lqc   = slq2[tin];

        // ---- pre-detect: z and D-addend for own 2 slots (r-independent) ----
        float e0 = eps[tin * K + j0];
        float e1 = eps[tin * K + j1];
        float z0 = fmaf(std_i, e0, mu_i);
        float z1 = fmaf(std_i, e1, mu_i);
        float a0 = fwd ? 0.0f : fmaf((0.5f * L2E_F) * e0, e0, lqc);
        float a1 = fwd ? 0.0f : fmaf((0.5f * L2E_F) * e1, e1, lqc);
        float d0 = fmaf((-16.0f * L2E_F) * z0, z0, a0);
        float d1 = fmaf((-16.0f * L2E_F) * z1, z1, a1);

        // ---- detection: wave 0 polls 128 packed sentinels (tight spin) ----
        if (wave == 0) {
            for (;;) {
                int v0 = sload(&mysent[lane]);
                int v1 = sload(&mysent[lane + 64]);
                if (__all(min(v0, v1) >= tg)) break;
            }
            __hip_atomic_store(&stepflag, tg, __ATOMIC_RELEASE,
                               __HIP_MEMORY_SCOPE_WORKGROUP);
        } else {
            while (__hip_atomic_load(&stepflag, __ATOMIC_ACQUIRE,
                                     __HIP_MEMORY_SCOPE_WORKGROUP) < tg) {}
        }

        // ---- LDS parity reuse guard: all waves consumed its previous use ----
        {
            const int need = tg - 2;
            for (;;) {
                int v = (lane < NWAVES)
                    ? __hip_atomic_load(&donef[par][lane], __ATOMIC_ACQUIRE,
                                        __HIP_MEMORY_SCOPE_WORKGROUP)
                    : 0x7fffffff;
                if (__all(v >= need)) break;
            }
        }

        // ---- one-shot read of OWN chunk (sentinel-gated), stage + flag ----
        float r0 = aload4(&mybuf[par * K + j0]);
        float r1 = aload4(&mybuf[par * K + j1]);
        shzD[par][j0] = make_float2(z0, r0 + d0);
        shzD[par][j1] = make_float2(z1, r1 + d1);
        __hip_atomic_store(&chunkflag[par][wave], tg, __ATOMIC_RELEASE,
                           __HIP_MEMORY_SCOPE_WORKGROUP);

        // ---- max pass: stream chunks round-robin in arrival order ----
        float2 zc = lzc[town][wave];
        float tz2 = zc.x, cm2 = zc.y;
        float u[32];
        float mM = -INFINITY;
        #pragma unroll
        for (int i = 0; i < 16; ++i) {
            int cw = (wave + i) & 15;
            if (i > 0) {
                while (__hip_atomic_load(&chunkflag[par][cw], __ATOMIC_ACQUIRE,
                                         __HIP_MEMORY_SCOPE_WORKGROUP) < tg) {}
            }
            float2 ca = shzD[par][cw * 128 + lane];
            float2 cb = shzD[par][cw * 128 + 64 + lane];
            u[2 * i]     = fmaf(tz2, ca.x, ca.y);   // rho_j - 16L2E(z'-z_j)^2 + c
            u[2 * i + 1] = fmaf(tz2, cb.x, cb.y);
            mM = fmaxf(mM, fmaxf(u[2 * i], u[2 * i + 1]));
        }
        __hip_atomic_store(&donef[par][wave], tg, __ATOMIC_RELEASE,
                           __HIP_MEMORY_SCOPE_WORKGROUP);

        #pragma unroll
        for (int off = 32; off >= 1; off >>= 1)
            mM = fmaxf(mM, __shfl_xor(mM, off, 64));
        float ss = 0.0f;
        #pragma unroll
        for (int i = 0; i < 32; ++i) ss += EXP2F(u[i] - mM);
        #pragma unroll
        for (int off = 32; off >= 1; off >>= 1)
            ss += __shfl_xor(ss, off, 64);

        // ---- publish own column; last-finishing wave fires the sentinel ----
        if (lane == 0)
            astore4(&mybuf[(par ^ 1) * K + col0 + wave], cm2 + mM + LOG2F(ss));
        asm volatile("s_waitcnt vmcnt(0)" ::: "memory");   // own publish at MALL
        if (lane == 0) {
            int old = __hip_atomic_fetch_add(&pubcnt[par], 1, __ATOMIC_ACQ_REL,
                                             __HIP_MEMORY_SCOPE_WORKGROUP);
            if (old == 16 * (p >> 1) + 15)      // 16th publish of this use
                sstore(&mysent[lb], tg + 1);
        }
    }

    // ---- join: out = lse_j(r_16[j] + c_16[j]) - lnK, block 0 only ----
    if (b == 0) {
        for (;;) {   // one-time poll of both directions, all waves
            int f0 = sload(&fsent[lane]);
            int f1 = sload(&fsent[lane + 64]);
            int g0 = sload(&bsent[lane]);
            int g1 = sload(&bsent[lane + 64]);
            bool ok = (min(f0, f1) >= 17) && (min(g0, g1) >= 16);
            if (__all(ok)) break;
            __builtin_amdgcn_s_sleep(1);
        }
        // r_16: fbuf parity 0 (last fwd step p=15 publishes into par^1=0)
        // c_16: bbuf parity 1 (last bwd step p=14 publishes into par^1=1)
        const int jA = tid, jB = tid + NTHREADS;
        float vA = aload4(&fbuf[jA]) + aload4(&bbuf[K + jA]);   // log2 domain
        float vB = aload4(&fbuf[jB]) + aload4(&bbuf[K + jB]);
        float m = fmaxf(vA, vB);
        red[tid] = m; __syncthreads();
        for (int off = NTHREADS / 2; off >= 1; off >>= 1) {
            if (tid < off) red[tid] = fmaxf(red[tid], red[tid + off]);
            __syncthreads();
        }
        m = red[0]; __syncthreads();
        float ssum = EXP2F(vA - m) + EXP2F(vB - m);
        red[tid] = ssum; __syncthreads();
        for (int off = NTHREADS / 2; off >= 1; off >>= 1) {
            if (tid < off) red[tid] += red[tid + off];
            __syncthreads();
        }
        if (tid == 0) out[0] = LN2_F * (m + LOG2F(red[0]) - 11.0f);
    }
}

extern "C" void kernel_launch(void* const* d_in, const int* in_sizes, int n_in,
                              void* d_out, int out_size, void* d_ws, size_t ws_size,
                              hipStream_t stream) {
    const float* means    = (const float*)d_in[0];
    const float* log_stds = (const float*)d_in[1];
    const float* eps      = (const float*)d_in[2];
    float* out = (float*)d_out;

    float* fbuf = (float*)d_ws;                 // 2*K fwd rho ping-pong (16 KB)
    float* bbuf = fbuf + 2 * K;                 // 2*K bwd rho ping-pong (16 KB)
    int*   fsent = (int*)(bbuf + 2 * K);        // 128 fwd sentinels (512 B)
    int*   bsent = fsent + 128;                 // 128 bwd sentinels (512 B)

    fused_kernel<<<NBLOCKS, NTHREADS, 0, stream>>>(
        means, log_stds, eps, fbuf, bbuf, fsent, bsent, out);
}

// Round 14
// 123.999 us; speedup vs baseline: 1.3979x; 1.3979x over previous
//
#include <hip/hip_runtime.h>
#include <math.h>

#define T 32
#define K 2048
#define NBLOCKS 256
#define NTHREADS 1024
#define NWAVES 16
#define HB 128                          // blocks per direction
#define CPB 16                          // columns per block (1 per wave)
#define QS 2                            // K / NTHREADS slots per thread
#define L2E_F 1.4426950408889634f       // log2(e)
#define LN2_F 0.6931471805599453f
#define LOG2PI_F 1.8378770664093453f
#define SP_F     0.17677669529663687f   // sqrt(1/32)
#define LOG_SP_F (-1.7328679513998633f) // ln(sqrt(1/32))
#define CNORM_F  (-(LOG_SP_F) - 0.5f * LOG2PI_F)   // -ln(sp) - 0.5 ln2pi

#if __has_builtin(__builtin_amdgcn_exp2f)
#define EXP2F(x) __builtin_amdgcn_exp2f(x)
#else
#define EXP2F(x) exp2f(x)
#endif
#if __has_builtin(__builtin_amdgcn_logf)
#define LOG2F(x) __builtin_amdgcn_logf(x)
#else
#define LOG2F(x) log2f(x)
#endif

// ALL global sync traffic is relaxed agent-scope atomics (write-through to
// the MALL, bypassing non-coherent per-XCD L2s). NO agent-scope
// release/acquire anywhere (R2/R7: ~15us/step of L2 cache maintenance).
// Producer ordering (data before sentinel) = __syncthreads' per-wave vmcnt
// drain before s_barrier.
__device__ __forceinline__ float aload4(const float* p) {
    return __hip_atomic_load(p, __ATOMIC_RELAXED, __HIP_MEMORY_SCOPE_AGENT);
}
__device__ __forceinline__ void astore4(float* p, float v) {
    __hip_atomic_store(p, v, __ATOMIC_RELAXED, __HIP_MEMORY_SCOPE_AGENT);
}
__device__ __forceinline__ int sload(const int* p) {
    return __hip_atomic_load(p, __ATOMIC_RELAXED, __HIP_MEMORY_SCOPE_AGENT);
}
__device__ __forceinline__ void sstore(int* p, int v) {
    __hip_atomic_store(p, v, __ATOMIC_RELAXED, __HIP_MEMORY_SCOPE_AGENT);
}

// R11's proven structure (best: 70us kernel) with ONE change: 1024 threads,
// 16 waves, ONE column per wave (halves the per-wave compute tail and
// per-thread staging). Everything else identical to R11:
// Bidirectional meet-in-the-middle — blocks 0..127 run the FORWARD chain
// (r_1..r_16), blocks 128..255 the BACKWARD chain (c_30..c_16 seeded by the
// likelihood c_31); out = lse_j(r_16[j]+c_16[j]) - lnK. 16-step critical
// path. Per direction: 128 sentinels packed in 4 MALL lines, ONE polling
// wave per block (R10: all-wave polling serializes at the MALL), LDS-flag
// handoff (workgroup scope, lgkmcnt-only), parallel one-shot read of the
// 2048-float message row (R12: per-wave tag re-polling quadruples FETCH),
// two plain block barriers (R13: replacing them with LDS flag machinery
// costs more than s_barrier). Signed sentinels 1..17: the 0xAAAAAAAA
// poison is negative, never satisfies >=, so no init kernel. Ping-pong
// safety: advancing to step p+2 requires observing all sentinels >= p+1,
// hence every block consumed step p — rows never overwritten while
// readable. Chain state carried in log2 domain.
__global__ __launch_bounds__(NTHREADS) void fused_kernel(
    const float* __restrict__ means, const float* __restrict__ log_stds,
    const float* __restrict__ eps, float* __restrict__ fbuf,
    float* __restrict__ bbuf, int* __restrict__ fsent, int* __restrict__ bsent,
    float* __restrict__ out)
{
    __shared__ float2 shzD[2][K];    // 32 KB: (z_j, D_j) staging, parity dbuf
    __shared__ float2 lzc[T][CPB];   // own cols: (32*L2E*z, cm2 const)
    __shared__ float smu[T], sstd[T], slq2[T];
    __shared__ float red[NTHREADS];
    __shared__ int ldsflag;

    const int tid  = threadIdx.x;
    const int b    = blockIdx.x;
    const bool fwd = (b < HB);
    const int lb   = fwd ? b : b - HB;
    const int col0 = lb * CPB;

    if (tid == 0) ldsflag = 0;

    // ---- setup: threads 0..511, thread (t = tid>>4, dcol = tid&15) ----
    if (tid < T * CPB) {
        int t = tid >> 4, dcol = tid & 15;
        float mu = means[t];
        float st = expf(log_stds[t]);
        if (dcol == 0) {
            smu[t] = mu; sstd[t] = st;
            slq2[t] = L2E_F * (logf(st) + 0.5f * LOG2PI_F);
        }
        float e = eps[t * K + col0 + dcol];
        float z = fmaf(st, e, mu);
        // (z-mu)/st == e exactly: log_q = -0.5 e^2 - ln(st) - 0.5 ln2pi
        float log_q = fmaf(-0.5f * e, e, -logf(st) - 0.5f * LOG2PI_F);
        float tz2 = (32.0f * L2E_F) * z;
        if (fwd) {
            float cm2 = fmaf((-16.0f * L2E_F) * z, z,
                             L2E_F * (CNORM_F - log_q)) - 11.0f;   // log2K = 11
            lzc[t][dcol] = make_float2(tz2, cm2);
            if (t == 0) {   // seed r_0, parity 0
                float r0 = fmaf(-16.0f * z, z, CNORM_F) - log_q;
                astore4(&fbuf[col0 + dcol], r0 * L2E_F);
            }
        } else {
            float cm2 = fmaf((-16.0f * L2E_F) * z, z, L2E_F * CNORM_F) - 11.0f;
            lzc[t][dcol] = make_float2(tz2, cm2);
            if (t == T - 1) {   // seed c_31 = likelihood, parity 0
                float d = 0.5f - z;
                float c31 = fmaf(-0.5f * d, d, -0.5f * LOG2PI_F);
                astore4(&bbuf[col0 + dcol], c31 * L2E_F);
            }
        }
    }
    __syncthreads();               // drains seed stores (vmcnt) + LDS init
    int* mysent = fwd ? fsent : bsent;
    if (tid == 0) sstore(&mysent[lb], 1);

    const int lane = tid & 63;
    const int wave = tid >> 6;     // 0..15: column col0 + wave
    float* mybuf = fwd ? fbuf : bbuf;
    const int nstep = fwd ? 16 : 15;

    for (int p = 0; p < nstep; ++p) {
        const int par  = p & 1;
        const int need = p + 1;
        const int tin  = fwd ? p : 31 - p;
        const int town = fwd ? p + 1 : 30 - p;
        const float mu_i  = smu[tin];
        const float std_i = sstd[tin];
        const float lqc   = slq2[tin];
        const float* erow = eps + tin * K;

        // ---- pre-poll: z + D-addend for own QS slots (r-independent) ----
        float zloc[QS], dadd[QS];
        #pragma unroll
        for (int q = 0; q < QS; ++q) {
            float e = erow[tid + q * NTHREADS];
            float z = fmaf(std_i, e, mu_i);
            zloc[q] = z;
            float base = fwd ? 0.0f : fmaf((0.5f * L2E_F) * e, e, lqc);
            dadd[q] = fmaf((-16.0f * L2E_F) * z, z, base);
        }

        // ---- detection: wave 0 polls own direction's 128 packed sentinels ----
        if (wave == 0) {
            for (;;) {
                int v0 = sload(&mysent[lane]);
                int v1 = sload(&mysent[lane + 64]);
                if (__all(min(v0, v1) >= need)) break;
                __builtin_amdgcn_s_sleep(1);
            }
            __hip_atomic_store(&ldsflag, need, __ATOMIC_RELEASE,
                               __HIP_MEMORY_SCOPE_WORKGROUP);
        } else {
            while (__hip_atomic_load(&ldsflag, __ATOMIC_ACQUIRE,
                                     __HIP_MEMORY_SCOPE_WORKGROUP) < need)
                __builtin_amdgcn_s_sleep(1);
        }

        // ---- one-shot parallel read of the message row + LDS stage ----
        const float* mrow = mybuf + par * K;
        float rv[QS];
        #pragma unroll
        for (int q = 0; q < QS; ++q) rv[q] = aload4(&mrow[tid + q * NTHREADS]);
        #pragma unroll
        for (int q = 0; q < QS; ++q)
            shzD[par][tid + q * NTHREADS] = make_float2(zloc[q], rv[q] + dadd[q]);
        __syncthreads();   // barrier A: stage ready

        // ---- this wave's ONE column: max pass + exp2 pass ----
        const float4* shp = (const float4*)&shzD[par][0];
        float2 zc = lzc[town][wave];
        float tz2 = zc.x, cm2 = zc.y;
        float u[32];
        float mM = -INFINITY;
        #pragma unroll
        for (int i = 0; i < 16; ++i) {
            float4 f4 = shp[lane + (i << 6)];
            // u_j = rho_j - 16*L2E*(z'-z_j)^2 + const = fma(tz2, z_j, D_j)
            u[2 * i]     = fmaf(tz2, f4.x, f4.y);
            u[2 * i + 1] = fmaf(tz2, f4.z, f4.w);
            mM = fmaxf(mM, fmaxf(u[2 * i], u[2 * i + 1]));
        }
        #pragma unroll
        for (int off = 32; off >= 1; off >>= 1)
            mM = fmaxf(mM, __shfl_xor(mM, off, 64));
        float ss = 0.0f;
        #pragma unroll
        for (int i = 0; i < 32; ++i) ss += EXP2F(u[i] - mM);
        #pragma unroll
        for (int off = 32; off >= 1; off >>= 1)
            ss += __shfl_xor(ss, off, 64);
        if (lane == 0)
            astore4(&mybuf[(par ^ 1) * K + col0 + wave], cm2 + mM + LOG2F(ss));

        // barrier B drains every wave's publish (vmcnt) before s_barrier;
        // only then this block's sentinel advances.
        __syncthreads();
        if (tid == 0) sstore(&mysent[lb], p + 2);
    }

    // ---- join: out = lse_j(r_16[j] + c_16[j]) - lnK, block 0 only ----
    if (b == 0) {
        for (;;) {   // one-time poll of both directions, all waves
            int f0 = sload(&fsent[lane]);
            int f1 = sload(&fsent[lane + 64]);
            int g0 = sload(&bsent[lane]);
            int g1 = sload(&bsent[lane + 64]);
            bool ok = (min(f0, f1) >= 17) && (min(g0, g1) >= 16);
            if (__all(ok)) break;
            __builtin_amdgcn_s_sleep(1);
        }
        // r_16: fbuf parity 0 (last fwd step p=15 -> par^1 = 0)
        // c_16: bbuf parity 1 (last bwd step p=14 -> par^1 = 1)
        const int jA = tid, jB = tid + NTHREADS;
        float vA = aload4(&fbuf[jA]) + aload4(&bbuf[K + jA]);   // log2 domain
        float vB = aload4(&fbuf[jB]) + aload4(&bbuf[K + jB]);
        float m = fmaxf(vA, vB);
        red[tid] = m; __syncthreads();
        for (int off = NTHREADS / 2; off >= 1; off >>= 1) {
            if (tid < off) red[tid] = fmaxf(red[tid], red[tid + off]);
            __syncthreads();
        }
        m = red[0]; __syncthreads();
        float ssum = EXP2F(vA - m) + EXP2F(vB - m);
        red[tid] = ssum; __syncthreads();
        for (int off = NTHREADS / 2; off >= 1; off >>= 1) {
            if (tid < off) red[tid] += red[tid + off];
            __syncthreads();
        }
        if (tid == 0) out[0] = LN2_F * (m + LOG2F(red[0]) - 11.0f);
    }
}

extern "C" void kernel_launch(void* const* d_in, const int* in_sizes, int n_in,
                              void* d_out, int out_size, void* d_ws, size_t ws_size,
                              hipStream_t stream) {
    const float* means    = (const float*)d_in[0];
    const float* log_stds = (const float*)d_in[1];
    const float* eps      = (const float*)d_in[2];
    float* out = (float*)d_out;

    float* fbuf = (float*)d_ws;                 // 2*K fwd rho ping-pong (16 KB)
    float* bbuf = fbuf + 2 * K;                 // 2*K bwd rho ping-pong (16 KB)
    int*   fsent = (int*)(bbuf + 2 * K);        // 128 fwd sentinels (512 B)
    int*   bsent = fsent + 128;                 // 128 bwd sentinels (512 B)

    fused_kernel<<<NBLOCKS, NTHREADS, 0, stream>>>(
        means, log_stds, eps, fbuf, bbuf, fsent, bsent, out);
}

// Round 15
// 114.507 us; speedup vs baseline: 1.5138x; 1.0829x over previous
//
#include <hip/hip_runtime.h>
#include <math.h>

#define T 32
#define K 2048
#define NBLOCKS 256
#define NTHREADS 512
#define HB 128                          // blocks per direction
#define CPB 16                          // columns per block (2 per wave)
#define QS 4                            // K / NTHREADS slots per thread
#define SSTRIDE 32                      // ints: 128 B -> one MALL line per sentinel
#define L2E_F 1.4426950408889634f       // log2(e)
#define LN2_F 0.6931471805599453f
#define LOG2PI_F 1.8378770664093453f
#define SP_F     0.17677669529663687f   // sqrt(1/32)
#define LOG_SP_F (-1.7328679513998633f) // ln(sqrt(1/32))
#define CNORM_F  (-(LOG_SP_F) - 0.5f * LOG2PI_F)   // -ln(sp) - 0.5 ln2pi

#if __has_builtin(__builtin_amdgcn_exp2f)
#define EXP2F(x) __builtin_amdgcn_exp2f(x)
#else
#define EXP2F(x) exp2f(x)
#endif
#if __has_builtin(__builtin_amdgcn_logf)
#define LOG2F(x) __builtin_amdgcn_logf(x)
#else
#define LOG2F(x) log2f(x)
#endif

// ALL global sync traffic is relaxed agent-scope atomics (write-through to
// the MALL, bypassing non-coherent per-XCD L2s). NO agent-scope
// release/acquire anywhere (R2/R7: ~15us/step of L2 cache maintenance).
// Producer ordering (data before sentinel) = __syncthreads' per-wave vmcnt
// drain before s_barrier.
__device__ __forceinline__ float aload4(const float* p) {
    return __hip_atomic_load(p, __ATOMIC_RELAXED, __HIP_MEMORY_SCOPE_AGENT);
}
__device__ __forceinline__ void astore4(float* p, float v) {
    __hip_atomic_store(p, v, __ATOMIC_RELAXED, __HIP_MEMORY_SCOPE_AGENT);
}
__device__ __forceinline__ int sload(const int* p) {
    return __hip_atomic_load(p, __ATOMIC_RELAXED, __HIP_MEMORY_SCOPE_AGENT);
}
__device__ __forceinline__ void sstore(int* p, int v) {
    __hip_atomic_store(p, v, __ATOMIC_RELAXED, __HIP_MEMORY_SCOPE_AGENT);
}

// R11's champion structure (70us kernel) with ONE change: sentinels SPREAD
// onto private 128B lines (R8's layout, the best measured detection
// constant at 3.17us/step) instead of packed into 4 hot lines. R10 showed
// same-line agent-scope accesses serialize at the coherence point; packed
// sentinels concentrate 128 stores + 256 polling waves onto 4 lines/dir.
// Spread lines absorb stores privately and spread poll loads across MALL
// slices; extra sweep fetch is harmless (R8: 6MB total).
//
// Bidirectional meet-in-the-middle: blocks 0..127 run the FORWARD chain
// (r_1..r_16), blocks 128..255 the BACKWARD chain (c_30..c_16 seeded by the
// likelihood c_31); out = lse_j(r_16[j]+c_16[j]) - lnK. 16-step critical
// path. Per direction: 128 one-line sentinels, ONE polling wave per block
// (R10: all-wave polling serializes), LDS-flag handoff (workgroup scope,
// lgkmcnt-only), parallel one-shot read of the 2048-float message row
// (R12: per-wave tag re-polling quadruples FETCH), two plain block barriers
// (R13: LDS flag machinery costs more than s_barrier). Signed sentinels
// 1..17: the 0xAAAAAAAA poison is negative, never satisfies >=, so no init
// kernel. Ping-pong safety: advancing to step p+2 requires observing all
// sentinels >= p+1, hence every block consumed step p — rows are never
// overwritten while readable. Chain state carried in log2 domain.
__global__ __launch_bounds__(NTHREADS) void fused_kernel(
    const float* __restrict__ means, const float* __restrict__ log_stds,
    const float* __restrict__ eps, float* __restrict__ fbuf,
    float* __restrict__ bbuf, int* __restrict__ fsent, int* __restrict__ bsent,
    float* __restrict__ out)
{
    __shared__ float2 shzD[2][K];    // 32 KB: (z_j, D_j) staging, parity dbuf
    __shared__ float2 lzc[T][CPB];   // own cols: (32*L2E*z, cm2 const)
    __shared__ float smu[T], sstd[T], slq2[T];
    __shared__ float red[NTHREADS];
    __shared__ int ldsflag;

    const int tid  = threadIdx.x;
    const int b    = blockIdx.x;
    const bool fwd = (b < HB);
    const int lb   = fwd ? b : b - HB;
    const int col0 = lb * CPB;

    if (tid == 0) ldsflag = 0;

    // ---- setup: thread (t = tid>>4, dcol = tid&15) handles (t, col0+dcol) ----
    {
        int t = tid >> 4, dcol = tid & 15;
        float mu = means[t];
        float st = expf(log_stds[t]);
        if (dcol == 0) {
            smu[t] = mu; sstd[t] = st;
            slq2[t] = L2E_F * (logf(st) + 0.5f * LOG2PI_F);
        }
        float e = eps[t * K + col0 + dcol];
        float z = fmaf(st, e, mu);
        // (z-mu)/st == e exactly: log_q = -0.5 e^2 - ln(st) - 0.5 ln2pi
        float log_q = fmaf(-0.5f * e, e, -logf(st) - 0.5f * LOG2PI_F);
        float tz2 = (32.0f * L2E_F) * z;
        if (fwd) {
            float cm2 = fmaf((-16.0f * L2E_F) * z, z,
                             L2E_F * (CNORM_F - log_q)) - 11.0f;   // log2K = 11
            lzc[t][dcol] = make_float2(tz2, cm2);
            if (t == 0) {   // seed r_0, parity 0
                float r0 = fmaf(-16.0f * z, z, CNORM_F) - log_q;
                astore4(&fbuf[col0 + dcol], r0 * L2E_F);
            }
        } else {
            float cm2 = fmaf((-16.0f * L2E_F) * z, z, L2E_F * CNORM_F) - 11.0f;
            lzc[t][dcol] = make_float2(tz2, cm2);
            if (t == T - 1) {   // seed c_31 = likelihood, parity 0
                float d = 0.5f - z;
                float c31 = fmaf(-0.5f * d, d, -0.5f * LOG2PI_F);
                astore4(&bbuf[col0 + dcol], c31 * L2E_F);
            }
        }
    }
    __syncthreads();               // drains seed stores (vmcnt) + LDS init
    int* mysent = fwd ? fsent : bsent;
    if (tid == 0) sstore(&mysent[lb * SSTRIDE], 1);

    const int lane = tid & 63;
    const int wave = tid >> 6;     // 0..7: columns 2w, 2w+1
    float* mybuf = fwd ? fbuf : bbuf;
    const int nstep = fwd ? 16 : 15;

    for (int p = 0; p < nstep; ++p) {
        const int par  = p & 1;
        const int need = p + 1;
        const int tin  = fwd ? p : 31 - p;
        const int town = fwd ? p + 1 : 30 - p;
        const float mu_i  = smu[tin];
        const float std_i = sstd[tin];
        const float lqc   = slq2[tin];
        const float* erow = eps + tin * K;

        // ---- pre-poll: z + D-addend for own QS slots (r-independent) ----
        float zloc[QS], dadd[QS];
        #pragma unroll
        for (int q = 0; q < QS; ++q) {
            float e = erow[tid + q * NTHREADS];
            float z = fmaf(std_i, e, mu_i);
            zloc[q] = z;
            float base = fwd ? 0.0f : fmaf((0.5f * L2E_F) * e, e, lqc);
            dadd[q] = fmaf((-16.0f * L2E_F) * z, z, base);
        }

        // ---- detection: wave 0 polls own direction's 128 one-line sentinels ----
        if (wave == 0) {
            const int* s0 = mysent + lane * SSTRIDE;
            const int* s1 = mysent + (lane + 64) * SSTRIDE;
            for (;;) {
                int v0 = sload(s0);
                int v1 = sload(s1);
                if (__all(min(v0, v1) >= need)) break;
                __builtin_amdgcn_s_sleep(1);
            }
            __hip_atomic_store(&ldsflag, need, __ATOMIC_RELEASE,
                               __HIP_MEMORY_SCOPE_WORKGROUP);
        } else {
            while (__hip_atomic_load(&ldsflag, __ATOMIC_ACQUIRE,
                                     __HIP_MEMORY_SCOPE_WORKGROUP) < need)
                __builtin_amdgcn_s_sleep(1);
        }

        // ---- one-shot parallel read of the message row + LDS stage ----
        const float* mrow = mybuf + par * K;
        float rv[QS];
        #pragma unroll
        for (int q = 0; q < QS; ++q) rv[q] = aload4(&mrow[tid + q * NTHREADS]);
        #pragma unroll
        for (int q = 0; q < QS; ++q)
            shzD[par][tid + q * NTHREADS] = make_float2(zloc[q], rv[q] + dadd[q]);
        __syncthreads();   // barrier A: stage ready

        // ---- this wave's 2 columns: max pass + exp2 pass over reg'd tiles ----
        const float4* shp = (const float4*)&shzD[par][0];
        float2 zcA = lzc[town][2 * wave];
        float2 zcB = lzc[town][2 * wave + 1];
        float4 fr[16];
        #pragma unroll
        for (int i = 0; i < 16; ++i) fr[i] = shp[lane + (i << 6)];
        float m0 = -INFINITY, m1 = -INFINITY;
        #pragma unroll
        for (int i = 0; i < 16; ++i) {
            m0 = fmaxf(m0, fmaxf(fmaf(zcA.x, fr[i].x, fr[i].y),
                                 fmaf(zcA.x, fr[i].z, fr[i].w)));
            m1 = fmaxf(m1, fmaxf(fmaf(zcB.x, fr[i].x, fr[i].y),
                                 fmaf(zcB.x, fr[i].z, fr[i].w)));
        }
        #pragma unroll
        for (int off = 32; off >= 1; off >>= 1) {
            m0 = fmaxf(m0, __shfl_xor(m0, off, 64));
            m1 = fmaxf(m1, __shfl_xor(m1, off, 64));
        }
        float s0 = 0.0f, s1 = 0.0f;
        #pragma unroll
        for (int i = 0; i < 16; ++i) {
            s0 += EXP2F(fmaf(zcA.x, fr[i].x, fr[i].y) - m0);
            s0 += EXP2F(fmaf(zcA.x, fr[i].z, fr[i].w) - m0);
            s1 += EXP2F(fmaf(zcB.x, fr[i].x, fr[i].y) - m1);
            s1 += EXP2F(fmaf(zcB.x, fr[i].z, fr[i].w) - m1);
        }
        #pragma unroll
        for (int off = 32; off >= 1; off >>= 1) {
            s0 += __shfl_xor(s0, off, 64);
            s1 += __shfl_xor(s1, off, 64);
        }
        if (lane < 2) {
            float mm = lane ? m1 : m0;
            float sv = lane ? s1 : s0;
            float cm = lane ? zcB.y : zcA.y;
            astore4(&mybuf[(par ^ 1) * K + col0 + 2 * wave + lane],
                    cm + mm + LOG2F(sv));
        }
        // barrier B drains every wave's publish (vmcnt) before s_barrier;
        // only then this block's sentinel advances.
        __syncthreads();
        if (tid == 0) sstore(&mysent[lb * SSTRIDE], p + 2);
    }

    // ---- join: out = lse_j(r_16[j] + c_16[j]) - lnK, block 0 only ----
    if (b == 0) {
        for (;;) {   // one-time poll of both directions, all waves
            int f0 = sload(&fsent[lane * SSTRIDE]);
            int f1 = sload(&fsent[(lane + 64) * SSTRIDE]);
            int g0 = sload(&bsent[lane * SSTRIDE]);
            int g1 = sload(&bsent[(lane + 64) * SSTRIDE]);
            bool ok = (min(f0, f1) >= 17) && (min(g0, g1) >= 16);
            if (__all(ok)) break;
            __builtin_amdgcn_s_sleep(1);
        }
        // r_16: fbuf parity 0 (last fwd step p=15 -> par^1 = 0)
        // c_16: bbuf parity 1 (last bwd step p=14 -> par^1 = 1)
        float vals[QS];
        float m = -INFINITY;
        #pragma unroll
        for (int q = 0; q < QS; ++q) {
            int j = tid + q * NTHREADS;
            float v = aload4(&fbuf[j]) + aload4(&bbuf[K + j]);   // log2 domain
            vals[q] = v;
            m = fmaxf(m, v);
        }
        red[tid] = m; __syncthreads();
        for (int off = NTHREADS / 2; off >= 1; off >>= 1) {
            if (tid < off) red[tid] = fmaxf(red[tid], red[tid + off]);
            __syncthreads();
        }
        m = red[0]; __syncthreads();
        float ssum = 0.0f;
        #pragma unroll
        for (int q = 0; q < QS; ++q) ssum += EXP2F(vals[q] - m);
        red[tid] = ssum; __syncthreads();
        for (int off = NTHREADS / 2; off >= 1; off >>= 1) {
            if (tid < off) red[tid] += red[tid + off];
            __syncthreads();
        }
        if (tid == 0) out[0] = LN2_F * (m + LOG2F(red[0]) - 11.0f);
    }
}

extern "C" void kernel_launch(void* const* d_in, const int* in_sizes, int n_in,
                              void* d_out, int out_size, void* d_ws, size_t ws_size,
                              hipStream_t stream) {
    const float* means    = (const float*)d_in[0];
    const float* log_stds = (const float*)d_in[1];
    const float* eps      = (const float*)d_in[2];
    float* out = (float*)d_out;

    float* fbuf = (float*)d_ws;                 // 2*K fwd rho ping-pong (16 KB)
    float* bbuf = fbuf + 2 * K;                 // 2*K bwd rho ping-pong (16 KB)
    int*   fsent = (int*)(bbuf + 2 * K);        // 128 fwd sentinels, 128 B apart (16 KB)
    int*   bsent = fsent + 128 * SSTRIDE;       // 128 bwd sentinels, 128 B apart (16 KB)

    fused_kernel<<<NBLOCKS, NTHREADS, 0, stream>>>(
        means, log_stds, eps, fbuf, bbuf, fsent, bsent, out);
}